// Round 1
// baseline (1026.700 us; speedup 1.0000x reference)
//
#include <hip/hip_runtime.h>
#include <cstdint>
#include <cstddef>

#define NN 50000
#define DIN 128
#define RR 4
#define EE 400000
#define TE (RR*EE)

// ---------------- setup kernels ----------------

__global__ __launch_bounds__(256) void k_degrees(const int* __restrict__ src,
                                                 const int* __restrict__ dst,
                                                 float* __restrict__ nsrc,
                                                 float* __restrict__ ndst,
                                                 int* __restrict__ indeg) {
    int i = blockIdx.x * 256 + threadIdx.x;
    if (i >= TE) return;
    int r = i / EE;
    int s = src[i], d = dst[i];
    atomicAdd(&nsrc[r * NN + s], 1.0f);
    atomicAdd(&ndst[r * NN + d], 1.0f);
    atomicAdd(&indeg[d], 1);
}

__global__ __launch_bounds__(256) void k_norms(float* __restrict__ nsrc,
                                               float* __restrict__ ndst) {
    int i = blockIdx.x * 256 + threadIdx.x;
    if (i >= RR * NN) return;
    nsrc[i] = 1.0f / sqrtf(fmaxf(nsrc[i], 1.0f));
    ndst[i] = 1.0f / sqrtf(fmaxf(ndst[i], 1.0f));
}

// single-block exclusive scan over in-degrees -> row_ptr (+ cursor copy)
__global__ __launch_bounds__(1024) void k_scan(const int* __restrict__ indeg,
                                               int* __restrict__ row_ptr,
                                               int* __restrict__ cursor) {
    __shared__ int part[1024];
    const int CH = (NN + 1023) / 1024;  // 49
    int t = threadIdx.x;
    int base = t * CH;
    int s = 0;
    for (int j = 0; j < CH; j++) {
        int idx = base + j;
        if (idx < NN) s += indeg[idx];
    }
    part[t] = s;
    __syncthreads();
    for (int off = 1; off < 1024; off <<= 1) {
        int v = (t >= off) ? part[t - off] : 0;
        __syncthreads();
        part[t] += v;
        __syncthreads();
    }
    int run = (t == 0) ? 0 : part[t - 1];
    for (int j = 0; j < CH; j++) {
        int idx = base + j;
        if (idx < NN) {
            row_ptr[idx] = run;
            cursor[idx] = run;
            run += indeg[idx];
        }
    }
    if (t == 1023) row_ptr[NN] = run;
}

// fill CSR: payload = src index (16b) | relation (2b); weight = nd[r][d]*ns[r][s]
__global__ __launch_bounds__(256) void k_fill(const int* __restrict__ src,
                                              const int* __restrict__ dst,
                                              const float* __restrict__ nsrc,
                                              const float* __restrict__ ndst,
                                              int* __restrict__ cursor,
                                              int* __restrict__ colp,
                                              float* __restrict__ wed) {
    int i = blockIdx.x * 256 + threadIdx.x;
    if (i >= TE) return;
    int r = i / EE;
    int s = src[i], d = dst[i];
    int pos = atomicAdd(&cursor[d], 1);
    colp[pos] = s | (r << 16);
    wed[pos] = nsrc[r * NN + s] * ndst[r * NN + d];
}

// ---------------- aggregation: one wave per dst node ----------------
// M[d][0:128]   = sum_e c[r_e][0]*w_e*h[s_e]
// M[d][128:256] = sum_e c[r_e][1]*w_e*h[s_e]
__global__ __launch_bounds__(256) void k_agg(const float* __restrict__ h,
                                             const int* __restrict__ row_ptr,
                                             const int* __restrict__ colp,
                                             const float* __restrict__ wed,
                                             const float* __restrict__ coeff,
                                             float* __restrict__ M) {
    int wave = (blockIdx.x * 256 + threadIdx.x) >> 6;
    int lane = threadIdx.x & 63;
    if (wave >= NN) return;

    float c0[RR], c1[RR];
#pragma unroll
    for (int r = 0; r < RR; r++) {
        c0[r] = coeff[r * 2 + 0];
        c1[r] = coeff[r * 2 + 1];
    }

    int e0 = row_ptr[wave], e1 = row_ptr[wave + 1];
    float2 a0 = make_float2(0.f, 0.f);
    float2 a1 = make_float2(0.f, 0.f);
    const float2* __restrict__ h2 = (const float2*)h;

    int e = e0;
    for (; e + 1 < e1; e += 2) {
        int p0 = colp[e], p1 = colp[e + 1];
        float w0 = wed[e], w1 = wed[e + 1];
        float2 hA = h2[(size_t)(p0 & 0xFFFF) * 64 + lane];
        float2 hB = h2[(size_t)(p1 & 0xFFFF) * 64 + lane];
        int rA = p0 >> 16, rB = p1 >> 16;
        float wa0 = c0[rA] * w0, wa1 = c1[rA] * w0;
        float wb0 = c0[rB] * w1, wb1 = c1[rB] * w1;
        a0.x += wa0 * hA.x; a0.y += wa0 * hA.y;
        a1.x += wa1 * hA.x; a1.y += wa1 * hA.y;
        a0.x += wb0 * hB.x; a0.y += wb0 * hB.y;
        a1.x += wb1 * hB.x; a1.y += wb1 * hB.y;
    }
    if (e < e1) {
        int p0 = colp[e];
        float w0 = wed[e];
        float2 hA = h2[(size_t)(p0 & 0xFFFF) * 64 + lane];
        int rA = p0 >> 16;
        float wa0 = c0[rA] * w0, wa1 = c1[rA] * w0;
        a0.x += wa0 * hA.x; a0.y += wa0 * hA.y;
        a1.x += wa1 * hA.x; a1.y += wa1 * hA.y;
    }

    float2* __restrict__ M2 = (float2*)M;
    M2[(size_t)wave * 128 + lane] = a0;
    M2[(size_t)wave * 128 + 64 + lane] = a1;
}

// ---------------- fp32 GEMM: C[N,BN] = A[N,256] @ B[256,BN], optional relu ----
// BM=64, BK=16, 256 threads, thread tile 4 x TN
template <int BN, int TN>
__global__ __launch_bounds__(256) void k_gemm(const float* __restrict__ A,
                                              const float* __restrict__ B,
                                              float* __restrict__ C,
                                              int relu) {
    const int K = 256;
    __shared__ float As[16][68];   // [k][m], padded, 16B-aligned rows (68*4=272=17*16)
    __shared__ float Bs[16][BN];   // [k][n]

    int tid = threadIdx.x;
    int bm = blockIdx.x * 64;
    const int TC = BN / TN;        // 16
    int tc = tid % TC;
    int tr = tid / TC;             // 0..15 -> rows tr*4 .. tr*4+3

    float acc[4][TN];
#pragma unroll
    for (int i = 0; i < 4; i++)
#pragma unroll
        for (int j = 0; j < TN; j++) acc[i][j] = 0.f;

    int ar = tid >> 2;             // 0..63
    int ak = (tid & 3) * 4;        // 0,4,8,12

    for (int k0 = 0; k0 < K; k0 += 16) {
        float4 av = make_float4(0.f, 0.f, 0.f, 0.f);
        int grow = bm + ar;
        if (grow < NN) av = *(const float4*)&A[(size_t)grow * K + k0 + ak];
        As[ak + 0][ar] = av.x;
        As[ak + 1][ar] = av.y;
        As[ak + 2][ar] = av.z;
        As[ak + 3][ar] = av.w;

#pragma unroll
        for (int i = 0; i < (16 * BN) / (256 * 4); i++) {
            int idx = tid + i * 256;
            int bk = idx / (BN / 4);
            int bn = (idx % (BN / 4)) * 4;
            *(float4*)&Bs[bk][bn] = *(const float4*)&B[(size_t)(k0 + bk) * BN + bn];
        }
        __syncthreads();

#pragma unroll
        for (int k = 0; k < 16; k++) {
            float4 a4 = *(const float4*)&As[k][tr * 4];
            float a[4] = {a4.x, a4.y, a4.z, a4.w};
            float b[TN];
#pragma unroll
            for (int j = 0; j < TN; j += 4) {
                float4 b4 = *(const float4*)&Bs[k][tc * TN + j];
                b[j] = b4.x; b[j + 1] = b4.y; b[j + 2] = b4.z; b[j + 3] = b4.w;
            }
#pragma unroll
            for (int i = 0; i < 4; i++)
#pragma unroll
                for (int j = 0; j < TN; j++) acc[i][j] += a[i] * b[j];
        }
        __syncthreads();
    }

#pragma unroll
    for (int i = 0; i < 4; i++) {
        int grow = bm + tr * 4 + i;
        if (grow < NN) {
#pragma unroll
            for (int j = 0; j < TN; j += 4) {
                float4 v;
                v.x = acc[i][j]; v.y = acc[i][j + 1]; v.z = acc[i][j + 2]; v.w = acc[i][j + 3];
                if (relu) {
                    v.x = fmaxf(v.x, 0.f); v.y = fmaxf(v.y, 0.f);
                    v.z = fmaxf(v.z, 0.f); v.w = fmaxf(v.w, 0.f);
                }
                *(float4*)&C[(size_t)grow * BN + tc * TN + j] = v;
            }
        }
    }
}

// ---------------- host ----------------

extern "C" void kernel_launch(void* const* d_in, const int* in_sizes, int n_in,
                              void* d_out, int out_size, void* d_ws, size_t ws_size,
                              hipStream_t stream) {
    const float* x      = (const float*)d_in[0];
    const int*   src    = (const int*)d_in[1];
    const int*   dst    = (const int*)d_in[2];
    const float* basis0 = (const float*)d_in[3];  // [2,128,128] == [256,128] flat
    const float* coeff0 = (const float*)d_in[4];  // [4,2]
    const float* basis1 = (const float*)d_in[5];
    const float* coeff1 = (const float*)d_in[6];
    const float* basis2 = (const float*)d_in[7];  // [2,128,64] == [256,64] flat
    const float* coeff2 = (const float*)d_in[8];
    float* out = (float*)d_out;

    char* p = (char*)d_ws;
    auto alloc = [&](size_t bytes) {
        char* r = p;
        p += (bytes + 255) & ~(size_t)255;
        return r;
    };
    float* nsrc    = (float*)alloc((size_t)RR * NN * 4);
    float* ndst    = (float*)alloc((size_t)RR * NN * 4);
    int*   indeg   = (int*)alloc((size_t)NN * 4);
    int*   row_ptr = (int*)alloc((size_t)(NN + 1) * 4);
    int*   cursor  = (int*)alloc((size_t)NN * 4);
    int*   colp    = (int*)alloc((size_t)TE * 4);
    float* wed     = (float*)alloc((size_t)TE * 4);
    float* M       = (float*)alloc((size_t)NN * 256 * 4);
    float* H       = (float*)alloc((size_t)NN * 128 * 4);

    // zero the counter region (nsrc, ndst, indeg are contiguous at ws start)
    hipMemsetAsync(d_ws, 0, (size_t)(2 * RR * NN + NN) * 4 + 1024, stream);

    k_degrees<<<(TE + 255) / 256, 256, 0, stream>>>(src, dst, nsrc, ndst, indeg);
    k_norms<<<(RR * NN + 255) / 256, 256, 0, stream>>>(nsrc, ndst);
    k_scan<<<1, 1024, 0, stream>>>(indeg, row_ptr, cursor);
    k_fill<<<(TE + 255) / 256, 256, 0, stream>>>(src, dst, nsrc, ndst, cursor, colp, wed);

    int aggBlocks = NN / 4;          // one wave per node, 4 waves/block
    int gemmBlocks = (NN + 63) / 64; // 782

    // layer 0: x -> M -> H (relu)
    k_agg<<<aggBlocks, 256, 0, stream>>>(x, row_ptr, colp, wed, coeff0, M);
    k_gemm<128, 8><<<gemmBlocks, 256, 0, stream>>>(M, basis0, H, 1);
    // layer 1: H -> M -> H (relu)
    k_agg<<<aggBlocks, 256, 0, stream>>>(H, row_ptr, colp, wed, coeff1, M);
    k_gemm<128, 8><<<gemmBlocks, 256, 0, stream>>>(M, basis1, H, 1);
    // layer 2: H -> M -> out (no relu)
    k_agg<<<aggBlocks, 256, 0, stream>>>(H, row_ptr, colp, wed, coeff2, M);
    k_gemm<64, 4><<<gemmBlocks, 256, 0, stream>>>(M, basis2, out, 0);
}

// Round 2
// 976.500 us; speedup vs baseline: 1.0514x; 1.0514x over previous
//
#include <hip/hip_runtime.h>
#include <cstdint>
#include <cstddef>

#define NN 50000
#define DIN 128
#define RR 4
#define EE 400000
#define TE (RR*EE)
#define HB 12500   // histogram bins per range (4 ranges * 12500 = 50000)

// ---------------- degree histograms: zero global atomics ----------------
// grid = 32 blocks: combo = bid>>2 (r*2+side), range = bid&3.
// Each block scans one relation's src or dst array (400000 ints) and
// histograms values in [range*HB, (range+1)*HB) into LDS, then plain-stores
// its privately-owned output range.
__global__ __launch_bounds__(1024) void k_hist(const int* __restrict__ src,
                                               const int* __restrict__ dst,
                                               int* __restrict__ cnt_src,
                                               int* __restrict__ cnt_dst) {
    __shared__ int bins[HB];
    int combo = blockIdx.x >> 2;
    int range = blockIdx.x & 3;
    int r = combo >> 1;
    int side = combo & 1;
    const int* arr = (side == 0 ? src : dst) + (size_t)r * EE;
    int lo = range * HB;
    for (int i = threadIdx.x; i < HB; i += 1024) bins[i] = 0;
    __syncthreads();
    const int4* a4 = (const int4*)arr;
    for (int i = threadIdx.x; i < EE / 4; i += 1024) {
        int4 v = a4[i];
        int t;
        t = v.x - lo; if ((unsigned)t < (unsigned)HB) atomicAdd(&bins[t], 1);
        t = v.y - lo; if ((unsigned)t < (unsigned)HB) atomicAdd(&bins[t], 1);
        t = v.z - lo; if ((unsigned)t < (unsigned)HB) atomicAdd(&bins[t], 1);
        t = v.w - lo; if ((unsigned)t < (unsigned)HB) atomicAdd(&bins[t], 1);
    }
    __syncthreads();
    int* outp = (side == 0 ? cnt_src : cnt_dst) + (size_t)r * NN + lo;
    for (int i = threadIdx.x; i < HB; i += 1024) outp[i] = bins[i];
}

// counts -> norms (separate float arrays; counts stay intact for k_scan)
__global__ __launch_bounds__(256) void k_norms(const int* __restrict__ cnt_src,
                                               const int* __restrict__ cnt_dst,
                                               float* __restrict__ nsrc,
                                               float* __restrict__ ndst) {
    int i = blockIdx.x * 256 + threadIdx.x;
    if (i >= RR * NN) return;
    nsrc[i] = 1.0f / sqrtf(fmaxf((float)cnt_src[i], 1.0f));
    ndst[i] = 1.0f / sqrtf(fmaxf((float)cnt_dst[i], 1.0f));
}

// single-block exclusive scan; indeg[d] computed on the fly as sum over
// relations of cnt_dst[r][d] -> row_ptr (+ cursor copy)
__global__ __launch_bounds__(1024) void k_scan(const int* __restrict__ cnt_dst,
                                               int* __restrict__ row_ptr,
                                               int* __restrict__ cursor) {
    __shared__ int part[1024];
    const int CH = (NN + 1023) / 1024;  // 49
    int t = threadIdx.x;
    int base = t * CH;
    int s = 0;
    for (int j = 0; j < CH; j++) {
        int idx = base + j;
        if (idx < NN)
            s += cnt_dst[idx] + cnt_dst[NN + idx] + cnt_dst[2 * NN + idx] + cnt_dst[3 * NN + idx];
    }
    part[t] = s;
    __syncthreads();
    for (int off = 1; off < 1024; off <<= 1) {
        int v = (t >= off) ? part[t - off] : 0;
        __syncthreads();
        part[t] += v;
        __syncthreads();
    }
    int run = (t == 0) ? 0 : part[t - 1];
    for (int j = 0; j < CH; j++) {
        int idx = base + j;
        if (idx < NN) {
            row_ptr[idx] = run;
            cursor[idx] = run;
            run += cnt_dst[idx] + cnt_dst[NN + idx] + cnt_dst[2 * NN + idx] + cnt_dst[3 * NN + idx];
        }
    }
    if (t == 1023) row_ptr[NN] = run;
}

// fill CSR: single packed 8B store per edge: hi32 = weight bits, lo32 = src | r<<16
__global__ __launch_bounds__(256) void k_fill(const int* __restrict__ src,
                                              const int* __restrict__ dst,
                                              const float* __restrict__ nsrc,
                                              const float* __restrict__ ndst,
                                              int* __restrict__ cursor,
                                              unsigned long long* __restrict__ edges) {
    int i = blockIdx.x * 256 + threadIdx.x;
    if (i >= TE) return;
    int r = i / EE;
    int s = src[i], d = dst[i];
    int pos = atomicAdd(&cursor[d], 1);
    float w = nsrc[r * NN + s] * ndst[r * NN + d];
    unsigned long long pk = ((unsigned long long)__float_as_uint(w) << 32)
                          | (unsigned)(s | (r << 16));
    edges[pos] = pk;
}

// ---------------- aggregation: one wave per dst node ----------------
// M[d][0:128]   = sum_e c[r_e][0]*w_e*h[s_e]
// M[d][128:256] = sum_e c[r_e][1]*w_e*h[s_e]
__global__ __launch_bounds__(256) void k_agg(const float* __restrict__ h,
                                             const int* __restrict__ row_ptr,
                                             const unsigned long long* __restrict__ edges,
                                             const float* __restrict__ coeff,
                                             float* __restrict__ M) {
    int wave = (blockIdx.x * 256 + threadIdx.x) >> 6;
    int lane = threadIdx.x & 63;
    if (wave >= NN) return;

    float c0[RR], c1[RR];
#pragma unroll
    for (int r = 0; r < RR; r++) {
        c0[r] = coeff[r * 2 + 0];
        c1[r] = coeff[r * 2 + 1];
    }

    int e0 = row_ptr[wave], e1 = row_ptr[wave + 1];
    float2 a0 = make_float2(0.f, 0.f);
    float2 a1 = make_float2(0.f, 0.f);
    const float2* __restrict__ h2 = (const float2*)h;

    int e = e0;
    for (; e + 1 < e1; e += 2) {
        unsigned long long pkA = edges[e], pkB = edges[e + 1];
        unsigned pA = (unsigned)pkA, pB = (unsigned)pkB;
        float w0 = __uint_as_float((unsigned)(pkA >> 32));
        float w1 = __uint_as_float((unsigned)(pkB >> 32));
        float2 hA = h2[(size_t)(pA & 0xFFFF) * 64 + lane];
        float2 hB = h2[(size_t)(pB & 0xFFFF) * 64 + lane];
        int rA = (pA >> 16) & 3, rB = (pB >> 16) & 3;
        float wa0 = c0[rA] * w0, wa1 = c1[rA] * w0;
        float wb0 = c0[rB] * w1, wb1 = c1[rB] * w1;
        a0.x += wa0 * hA.x; a0.y += wa0 * hA.y;
        a1.x += wa1 * hA.x; a1.y += wa1 * hA.y;
        a0.x += wb0 * hB.x; a0.y += wb0 * hB.y;
        a1.x += wb1 * hB.x; a1.y += wb1 * hB.y;
    }
    if (e < e1) {
        unsigned long long pkA = edges[e];
        unsigned pA = (unsigned)pkA;
        float w0 = __uint_as_float((unsigned)(pkA >> 32));
        float2 hA = h2[(size_t)(pA & 0xFFFF) * 64 + lane];
        int rA = (pA >> 16) & 3;
        float wa0 = c0[rA] * w0, wa1 = c1[rA] * w0;
        a0.x += wa0 * hA.x; a0.y += wa0 * hA.y;
        a1.x += wa1 * hA.x; a1.y += wa1 * hA.y;
    }

    float2* __restrict__ M2 = (float2*)M;
    M2[(size_t)wave * 128 + lane] = a0;
    M2[(size_t)wave * 128 + 64 + lane] = a1;
}

// ---------------- fp32 GEMM: C[N,BN] = A[N,256] @ B[256,BN], optional relu ----
// BM=64, BK=16, 256 threads, thread tile 4 x TN
template <int BN, int TN>
__global__ __launch_bounds__(256) void k_gemm(const float* __restrict__ A,
                                              const float* __restrict__ B,
                                              float* __restrict__ C,
                                              int relu) {
    const int K = 256;
    __shared__ float As[16][68];   // [k][m], padded
    __shared__ float Bs[16][BN];   // [k][n]

    int tid = threadIdx.x;
    int bm = blockIdx.x * 64;
    const int TC = BN / TN;        // 16
    int tc = tid % TC;
    int tr = tid / TC;             // 0..15 -> rows tr*4 .. tr*4+3

    float acc[4][TN];
#pragma unroll
    for (int i = 0; i < 4; i++)
#pragma unroll
        for (int j = 0; j < TN; j++) acc[i][j] = 0.f;

    int ar = tid >> 2;             // 0..63
    int ak = (tid & 3) * 4;        // 0,4,8,12

    for (int k0 = 0; k0 < K; k0 += 16) {
        float4 av = make_float4(0.f, 0.f, 0.f, 0.f);
        int grow = bm + ar;
        if (grow < NN) av = *(const float4*)&A[(size_t)grow * K + k0 + ak];
        As[ak + 0][ar] = av.x;
        As[ak + 1][ar] = av.y;
        As[ak + 2][ar] = av.z;
        As[ak + 3][ar] = av.w;

#pragma unroll
        for (int i = 0; i < (16 * BN) / (256 * 4); i++) {
            int idx = tid + i * 256;
            int bk = idx / (BN / 4);
            int bn = (idx % (BN / 4)) * 4;
            *(float4*)&Bs[bk][bn] = *(const float4*)&B[(size_t)(k0 + bk) * BN + bn];
        }
        __syncthreads();

#pragma unroll
        for (int k = 0; k < 16; k++) {
            float4 a4 = *(const float4*)&As[k][tr * 4];
            float a[4] = {a4.x, a4.y, a4.z, a4.w};
            float b[TN];
#pragma unroll
            for (int j = 0; j < TN; j += 4) {
                float4 b4 = *(const float4*)&Bs[k][tc * TN + j];
                b[j] = b4.x; b[j + 1] = b4.y; b[j + 2] = b4.z; b[j + 3] = b4.w;
            }
#pragma unroll
            for (int i = 0; i < 4; i++)
#pragma unroll
                for (int j = 0; j < TN; j++) acc[i][j] += a[i] * b[j];
        }
        __syncthreads();
    }

#pragma unroll
    for (int i = 0; i < 4; i++) {
        int grow = bm + tr * 4 + i;
        if (grow < NN) {
#pragma unroll
            for (int j = 0; j < TN; j += 4) {
                float4 v;
                v.x = acc[i][j]; v.y = acc[i][j + 1]; v.z = acc[i][j + 2]; v.w = acc[i][j + 3];
                if (relu) {
                    v.x = fmaxf(v.x, 0.f); v.y = fmaxf(v.y, 0.f);
                    v.z = fmaxf(v.z, 0.f); v.w = fmaxf(v.w, 0.f);
                }
                *(float4*)&C[(size_t)grow * BN + tc * TN + j] = v;
            }
        }
    }
}

// ---------------- host ----------------

extern "C" void kernel_launch(void* const* d_in, const int* in_sizes, int n_in,
                              void* d_out, int out_size, void* d_ws, size_t ws_size,
                              hipStream_t stream) {
    const float* x      = (const float*)d_in[0];
    const int*   src    = (const int*)d_in[1];
    const int*   dst    = (const int*)d_in[2];
    const float* basis0 = (const float*)d_in[3];  // [2,128,128] == [256,128] flat
    const float* coeff0 = (const float*)d_in[4];  // [4,2]
    const float* basis1 = (const float*)d_in[5];
    const float* coeff1 = (const float*)d_in[6];
    const float* basis2 = (const float*)d_in[7];  // [2,128,64] == [256,64] flat
    const float* coeff2 = (const float*)d_in[8];
    float* out = (float*)d_out;

    char* p = (char*)d_ws;
    auto alloc = [&](size_t bytes) {
        char* r = p;
        p += (bytes + 255) & ~(size_t)255;
        return r;
    };
    int*   cnt_src = (int*)alloc((size_t)RR * NN * 4);
    int*   cnt_dst = (int*)alloc((size_t)RR * NN * 4);
    float* nsrc    = (float*)alloc((size_t)RR * NN * 4);
    float* ndst    = (float*)alloc((size_t)RR * NN * 4);
    int*   row_ptr = (int*)alloc((size_t)(NN + 1) * 4);
    int*   cursor  = (int*)alloc((size_t)NN * 4);
    unsigned long long* edges = (unsigned long long*)alloc((size_t)TE * 8);
    float* M       = (float*)alloc((size_t)NN * 256 * 4);
    float* H       = (float*)alloc((size_t)NN * 128 * 4);

    // no memset needed: every buffer is fully written before first read

    k_hist<<<32, 1024, 0, stream>>>(src, dst, cnt_src, cnt_dst);
    k_norms<<<(RR * NN + 255) / 256, 256, 0, stream>>>(cnt_src, cnt_dst, nsrc, ndst);
    k_scan<<<1, 1024, 0, stream>>>(cnt_dst, row_ptr, cursor);
    k_fill<<<(TE + 255) / 256, 256, 0, stream>>>(src, dst, nsrc, ndst, cursor, edges);

    int aggBlocks = NN / 4;          // one wave per node, 4 waves/block
    int gemmBlocks = (NN + 63) / 64; // 782

    // layer 0: x -> M -> H (relu)
    k_agg<<<aggBlocks, 256, 0, stream>>>(x, row_ptr, edges, coeff0, M);
    k_gemm<128, 8><<<gemmBlocks, 256, 0, stream>>>(M, basis0, H, 1);
    // layer 1: H -> M -> H (relu)
    k_agg<<<aggBlocks, 256, 0, stream>>>(H, row_ptr, edges, coeff1, M);
    k_gemm<128, 8><<<gemmBlocks, 256, 0, stream>>>(M, basis1, H, 1);
    // layer 2: H -> M -> out (no relu)
    k_agg<<<aggBlocks, 256, 0, stream>>>(H, row_ptr, edges, coeff2, M);
    k_gemm<64, 4><<<gemmBlocks, 256, 0, stream>>>(M, basis2, out, 0);
}

// Round 3
// 700.389 us; speedup vs baseline: 1.4659x; 1.3942x over previous
//
#include <hip/hip_runtime.h>
#include <cstdint>
#include <cstddef>

#define NN 50000
#define DIN 128
#define RR 4
#define EE 400000
#define TE (RR*EE)
#define HB 12500   // histogram bins per range (4 ranges * 12500 = 50000)
#define SCB 196    // scan blocks: ceil(50000/256)

// ---------------- degree histograms: zero global atomics ----------------
__global__ __launch_bounds__(1024) void k_hist(const int* __restrict__ src,
                                               const int* __restrict__ dst,
                                               int* __restrict__ cnt_src,
                                               int* __restrict__ cnt_dst) {
    __shared__ int bins[HB];
    int combo = blockIdx.x >> 2;
    int range = blockIdx.x & 3;
    int r = combo >> 1;
    int side = combo & 1;
    const int* arr = (side == 0 ? src : dst) + (size_t)r * EE;
    int lo = range * HB;
    for (int i = threadIdx.x; i < HB; i += 1024) bins[i] = 0;
    __syncthreads();
    const int4* a4 = (const int4*)arr;
    for (int i = threadIdx.x; i < EE / 4; i += 1024) {
        int4 v = a4[i];
        int t;
        t = v.x - lo; if ((unsigned)t < (unsigned)HB) atomicAdd(&bins[t], 1);
        t = v.y - lo; if ((unsigned)t < (unsigned)HB) atomicAdd(&bins[t], 1);
        t = v.z - lo; if ((unsigned)t < (unsigned)HB) atomicAdd(&bins[t], 1);
        t = v.w - lo; if ((unsigned)t < (unsigned)HB) atomicAdd(&bins[t], 1);
    }
    __syncthreads();
    int* outp = (side == 0 ? cnt_src : cnt_dst) + (size_t)r * NN + lo;
    for (int i = threadIdx.x; i < HB; i += 1024) outp[i] = bins[i];
}

// counts -> norms
__global__ __launch_bounds__(256) void k_norms(const int* __restrict__ cnt_src,
                                               const int* __restrict__ cnt_dst,
                                               float* __restrict__ nsrc,
                                               float* __restrict__ ndst) {
    int i = blockIdx.x * 256 + threadIdx.x;
    if (i >= RR * NN) return;
    nsrc[i] = 1.0f / sqrtf(fmaxf((float)cnt_src[i], 1.0f));
    ndst[i] = 1.0f / sqrtf(fmaxf((float)cnt_dst[i], 1.0f));
}

// ---------------- 3-phase parallel scan of in-degrees ----------------
// indeg[i] = sum_r cnt_dst[r][i]
__global__ __launch_bounds__(256) void k_partial(const int* __restrict__ cnt_dst,
                                                 int* __restrict__ part) {
    __shared__ int s[256];
    int t = threadIdx.x;
    int i = blockIdx.x * 256 + t;
    int v = 0;
    if (i < NN)
        v = cnt_dst[i] + cnt_dst[NN + i] + cnt_dst[2 * NN + i] + cnt_dst[3 * NN + i];
    s[t] = v;
    __syncthreads();
    for (int off = 128; off > 0; off >>= 1) {
        if (t < off) s[t] += s[t + off];
        __syncthreads();
    }
    if (t == 0) part[blockIdx.x] = s[0];
}

__global__ __launch_bounds__(256) void k_scan_small(const int* __restrict__ part,
                                                    int* __restrict__ offs) {
    __shared__ int s[256];
    int t = threadIdx.x;
    s[t] = (t < SCB) ? part[t] : 0;
    __syncthreads();
    for (int off = 1; off < 256; off <<= 1) {
        int v = (t >= off) ? s[t - off] : 0;
        __syncthreads();
        s[t] += v;
        __syncthreads();
    }
    if (t < SCB) offs[t] = (t == 0) ? 0 : s[t - 1];
}

__global__ __launch_bounds__(256) void k_emit(const int* __restrict__ cnt_dst,
                                              const int* __restrict__ offs,
                                              int* __restrict__ row_ptr,
                                              int* __restrict__ cursor) {
    __shared__ int s[256];
    int t = threadIdx.x;
    int i = blockIdx.x * 256 + t;
    int v = 0;
    if (i < NN)
        v = cnt_dst[i] + cnt_dst[NN + i] + cnt_dst[2 * NN + i] + cnt_dst[3 * NN + i];
    s[t] = v;
    __syncthreads();
    for (int off = 1; off < 256; off <<= 1) {
        int u = (t >= off) ? s[t - off] : 0;
        __syncthreads();
        s[t] += u;
        __syncthreads();
    }
    if (i < NN) {
        int ex = offs[blockIdx.x] + s[t] - v;  // exclusive prefix
        row_ptr[i] = ex;
        cursor[i] = ex;
    }
    if (i == NN - 1) row_ptr[NN] = TE;
}

// fill CSR: single packed 8B store per edge: hi32 = weight bits, lo32 = src | r<<16
__global__ __launch_bounds__(256) void k_fill(const int* __restrict__ src,
                                              const int* __restrict__ dst,
                                              const float* __restrict__ nsrc,
                                              const float* __restrict__ ndst,
                                              int* __restrict__ cursor,
                                              unsigned long long* __restrict__ edges) {
    int i = blockIdx.x * 256 + threadIdx.x;
    if (i >= TE) return;
    int r = i / EE;
    int s = src[i], d = dst[i];
    int pos = atomicAdd(&cursor[d], 1);
    float w = nsrc[r * NN + s] * ndst[r * NN + d];
    unsigned long long pk = ((unsigned long long)__float_as_uint(w) << 32)
                          | (unsigned)(s | (r << 16));
    edges[pos] = pk;
}

// ---------------- aggregation: one wave per dst node ----------------
__global__ __launch_bounds__(256) void k_agg(const float* __restrict__ h,
                                             const int* __restrict__ row_ptr,
                                             const unsigned long long* __restrict__ edges,
                                             const float* __restrict__ coeff,
                                             float* __restrict__ M) {
    int wave = (blockIdx.x * 256 + threadIdx.x) >> 6;
    int lane = threadIdx.x & 63;
    if (wave >= NN) return;

    float c0[RR], c1[RR];
#pragma unroll
    for (int r = 0; r < RR; r++) {
        c0[r] = coeff[r * 2 + 0];
        c1[r] = coeff[r * 2 + 1];
    }

    int e0 = row_ptr[wave], e1 = row_ptr[wave + 1];
    float2 a0 = make_float2(0.f, 0.f);
    float2 a1 = make_float2(0.f, 0.f);
    const float2* __restrict__ h2 = (const float2*)h;

    int e = e0;
    for (; e + 1 < e1; e += 2) {
        unsigned long long pkA = edges[e], pkB = edges[e + 1];
        unsigned pA = (unsigned)pkA, pB = (unsigned)pkB;
        float w0 = __uint_as_float((unsigned)(pkA >> 32));
        float w1 = __uint_as_float((unsigned)(pkB >> 32));
        float2 hA = h2[(size_t)(pA & 0xFFFF) * 64 + lane];
        float2 hB = h2[(size_t)(pB & 0xFFFF) * 64 + lane];
        int rA = (pA >> 16) & 3, rB = (pB >> 16) & 3;
        float wa0 = c0[rA] * w0, wa1 = c1[rA] * w0;
        float wb0 = c0[rB] * w1, wb1 = c1[rB] * w1;
        a0.x += wa0 * hA.x; a0.y += wa0 * hA.y;
        a1.x += wa1 * hA.x; a1.y += wa1 * hA.y;
        a0.x += wb0 * hB.x; a0.y += wb0 * hB.y;
        a1.x += wb1 * hB.x; a1.y += wb1 * hB.y;
    }
    if (e < e1) {
        unsigned long long pkA = edges[e];
        unsigned pA = (unsigned)pkA;
        float w0 = __uint_as_float((unsigned)(pkA >> 32));
        float2 hA = h2[(size_t)(pA & 0xFFFF) * 64 + lane];
        int rA = (pA >> 16) & 3;
        float wa0 = c0[rA] * w0, wa1 = c1[rA] * w0;
        a0.x += wa0 * hA.x; a0.y += wa0 * hA.y;
        a1.x += wa1 * hA.x; a1.y += wa1 * hA.y;
    }

    float2* __restrict__ M2 = (float2*)M;
    M2[(size_t)wave * 128 + lane] = a0;
    M2[(size_t)wave * 128 + 64 + lane] = a1;
}

// ---------------- fp32 GEMM: C[N,BN] = A[N,256] @ B[256,BN], optional relu ----
template <int BN, int TN>
__global__ __launch_bounds__(256) void k_gemm(const float* __restrict__ A,
                                              const float* __restrict__ B,
                                              float* __restrict__ C,
                                              int relu) {
    const int K = 256;
    __shared__ float As[16][68];
    __shared__ float Bs[16][BN];

    int tid = threadIdx.x;
    int bm = blockIdx.x * 64;
    const int TC = BN / TN;        // 16
    int tc = tid % TC;
    int tr = tid / TC;

    float acc[4][TN];
#pragma unroll
    for (int i = 0; i < 4; i++)
#pragma unroll
        for (int j = 0; j < TN; j++) acc[i][j] = 0.f;

    int ar = tid >> 2;
    int ak = (tid & 3) * 4;

    for (int k0 = 0; k0 < K; k0 += 16) {
        float4 av = make_float4(0.f, 0.f, 0.f, 0.f);
        int grow = bm + ar;
        if (grow < NN) av = *(const float4*)&A[(size_t)grow * K + k0 + ak];
        As[ak + 0][ar] = av.x;
        As[ak + 1][ar] = av.y;
        As[ak + 2][ar] = av.z;
        As[ak + 3][ar] = av.w;

#pragma unroll
        for (int i = 0; i < (16 * BN) / (256 * 4); i++) {
            int idx = tid + i * 256;
            int bk = idx / (BN / 4);
            int bn = (idx % (BN / 4)) * 4;
            *(float4*)&Bs[bk][bn] = *(const float4*)&B[(size_t)(k0 + bk) * BN + bn];
        }
        __syncthreads();

#pragma unroll
        for (int k = 0; k < 16; k++) {
            float4 a4 = *(const float4*)&As[k][tr * 4];
            float a[4] = {a4.x, a4.y, a4.z, a4.w};
            float b[TN];
#pragma unroll
            for (int j = 0; j < TN; j += 4) {
                float4 b4 = *(const float4*)&Bs[k][tc * TN + j];
                b[j] = b4.x; b[j + 1] = b4.y; b[j + 2] = b4.z; b[j + 3] = b4.w;
            }
#pragma unroll
            for (int i = 0; i < 4; i++)
#pragma unroll
                for (int j = 0; j < TN; j++) acc[i][j] += a[i] * b[j];
        }
        __syncthreads();
    }

#pragma unroll
    for (int i = 0; i < 4; i++) {
        int grow = bm + tr * 4 + i;
        if (grow < NN) {
#pragma unroll
            for (int j = 0; j < TN; j += 4) {
                float4 v;
                v.x = acc[i][j]; v.y = acc[i][j + 1]; v.z = acc[i][j + 2]; v.w = acc[i][j + 3];
                if (relu) {
                    v.x = fmaxf(v.x, 0.f); v.y = fmaxf(v.y, 0.f);
                    v.z = fmaxf(v.z, 0.f); v.w = fmaxf(v.w, 0.f);
                }
                *(float4*)&C[(size_t)grow * BN + tc * TN + j] = v;
            }
        }
    }
}

// ---------------- host ----------------

extern "C" void kernel_launch(void* const* d_in, const int* in_sizes, int n_in,
                              void* d_out, int out_size, void* d_ws, size_t ws_size,
                              hipStream_t stream) {
    const float* x      = (const float*)d_in[0];
    const int*   src    = (const int*)d_in[1];
    const int*   dst    = (const int*)d_in[2];
    const float* basis0 = (const float*)d_in[3];
    const float* coeff0 = (const float*)d_in[4];
    const float* basis1 = (const float*)d_in[5];
    const float* coeff1 = (const float*)d_in[6];
    const float* basis2 = (const float*)d_in[7];
    const float* coeff2 = (const float*)d_in[8];
    float* out = (float*)d_out;

    char* p = (char*)d_ws;
    auto alloc = [&](size_t bytes) {
        char* r = p;
        p += (bytes + 255) & ~(size_t)255;
        return r;
    };
    int*   cnt_src = (int*)alloc((size_t)RR * NN * 4);
    int*   cnt_dst = (int*)alloc((size_t)RR * NN * 4);
    float* nsrc    = (float*)alloc((size_t)RR * NN * 4);
    float* ndst    = (float*)alloc((size_t)RR * NN * 4);
    int*   row_ptr = (int*)alloc((size_t)(NN + 1) * 4);
    int*   cursor  = (int*)alloc((size_t)NN * 4);
    int*   part    = (int*)alloc((size_t)SCB * 4);
    int*   offs    = (int*)alloc((size_t)SCB * 4);
    unsigned long long* edges = (unsigned long long*)alloc((size_t)TE * 8);
    float* M       = (float*)alloc((size_t)NN * 256 * 4);
    float* H       = (float*)alloc((size_t)NN * 128 * 4);

    k_hist<<<32, 1024, 0, stream>>>(src, dst, cnt_src, cnt_dst);
    k_norms<<<(RR * NN + 255) / 256, 256, 0, stream>>>(cnt_src, cnt_dst, nsrc, ndst);
    k_partial<<<SCB, 256, 0, stream>>>(cnt_dst, part);
    k_scan_small<<<1, 256, 0, stream>>>(part, offs);
    k_emit<<<SCB, 256, 0, stream>>>(cnt_dst, offs, row_ptr, cursor);
    k_fill<<<(TE + 255) / 256, 256, 0, stream>>>(src, dst, nsrc, ndst, cursor, edges);

    int aggBlocks = NN / 4;
    int gemmBlocks = (NN + 63) / 64;

    // layer 0: x -> M -> H (relu)
    k_agg<<<aggBlocks, 256, 0, stream>>>(x, row_ptr, edges, coeff0, M);
    k_gemm<128, 8><<<gemmBlocks, 256, 0, stream>>>(M, basis0, H, 1);
    // layer 1: H -> M -> H (relu)
    k_agg<<<aggBlocks, 256, 0, stream>>>(H, row_ptr, edges, coeff1, M);
    k_gemm<128, 8><<<gemmBlocks, 256, 0, stream>>>(M, basis1, H, 1);
    // layer 2: H -> M -> out (no relu)
    k_agg<<<aggBlocks, 256, 0, stream>>>(H, row_ptr, edges, coeff2, M);
    k_gemm<64, 4><<<gemmBlocks, 256, 0, stream>>>(M, basis2, out, 0);
}

// Round 4
// 522.373 us; speedup vs baseline: 1.9655x; 1.3408x over previous
//
#include <hip/hip_runtime.h>
#include <hip/hip_bf16.h>
#include <cstdint>
#include <cstddef>

#define NN 50000
#define RR 4
#define EE 400000
#define TE (RR*EE)
#define HB 6250    // histogram bins per range (8 ranges * 6250 = 50000)
#define SCB 196    // scan blocks: ceil(50000/256)

using frag_ab = __attribute__((ext_vector_type(8))) short;   // 8 bf16 (4 VGPRs)
using frag_cd = __attribute__((ext_vector_type(4))) float;   // 4 fp32

static __device__ __forceinline__ unsigned short f2bf(float f) {
    union { float f; unsigned u; } v; v.f = f;
    unsigned r = (v.u + 0x7FFF + ((v.u >> 16) & 1)) >> 16;   // RNE
    return (unsigned short)r;
}
static __device__ __forceinline__ unsigned pack2(float lo, float hi) {
    return (unsigned)f2bf(lo) | ((unsigned)f2bf(hi) << 16);
}

// ---------------- degree histograms: zero global atomics ----------------
// 64 blocks: combo = bid>>3 (r*2+side), range = bid&7
__global__ __launch_bounds__(1024) void k_hist(const int* __restrict__ src,
                                               const int* __restrict__ dst,
                                               int* __restrict__ cnt_src,
                                               int* __restrict__ cnt_dst) {
    __shared__ int bins[HB];
    int combo = blockIdx.x >> 3;
    int range = blockIdx.x & 7;
    int r = combo >> 1;
    int side = combo & 1;
    const int* arr = (side == 0 ? src : dst) + (size_t)r * EE;
    int lo = range * HB;
    for (int i = threadIdx.x; i < HB; i += 1024) bins[i] = 0;
    __syncthreads();
    const int4* a4 = (const int4*)arr;
    for (int i = threadIdx.x; i < EE / 4; i += 1024) {
        int4 v = a4[i];
        int t;
        t = v.x - lo; if ((unsigned)t < (unsigned)HB) atomicAdd(&bins[t], 1);
        t = v.y - lo; if ((unsigned)t < (unsigned)HB) atomicAdd(&bins[t], 1);
        t = v.z - lo; if ((unsigned)t < (unsigned)HB) atomicAdd(&bins[t], 1);
        t = v.w - lo; if ((unsigned)t < (unsigned)HB) atomicAdd(&bins[t], 1);
    }
    __syncthreads();
    int* outp = (side == 0 ? cnt_src : cnt_dst) + (size_t)r * NN + lo;
    for (int i = threadIdx.x; i < HB; i += 1024) outp[i] = bins[i];
}

__global__ __launch_bounds__(256) void k_norms(const int* __restrict__ cnt_src,
                                               const int* __restrict__ cnt_dst,
                                               float* __restrict__ nsrc,
                                               float* __restrict__ ndst) {
    int i = blockIdx.x * 256 + threadIdx.x;
    if (i >= RR * NN) return;
    nsrc[i] = 1.0f / sqrtf(fmaxf((float)cnt_src[i], 1.0f));
    ndst[i] = 1.0f / sqrtf(fmaxf((float)cnt_dst[i], 1.0f));
}

// ---------------- 3-phase parallel scan of in-degrees ----------------
__global__ __launch_bounds__(256) void k_partial(const int* __restrict__ cnt_dst,
                                                 int* __restrict__ part) {
    __shared__ int s[256];
    int t = threadIdx.x;
    int i = blockIdx.x * 256 + t;
    int v = 0;
    if (i < NN)
        v = cnt_dst[i] + cnt_dst[NN + i] + cnt_dst[2 * NN + i] + cnt_dst[3 * NN + i];
    s[t] = v;
    __syncthreads();
    for (int off = 128; off > 0; off >>= 1) {
        if (t < off) s[t] += s[t + off];
        __syncthreads();
    }
    if (t == 0) part[blockIdx.x] = s[0];
}

__global__ __launch_bounds__(256) void k_scan_small(const int* __restrict__ part,
                                                    int* __restrict__ offs) {
    __shared__ int s[256];
    int t = threadIdx.x;
    s[t] = (t < SCB) ? part[t] : 0;
    __syncthreads();
    for (int off = 1; off < 256; off <<= 1) {
        int v = (t >= off) ? s[t - off] : 0;
        __syncthreads();
        s[t] += v;
        __syncthreads();
    }
    if (t < SCB) offs[t] = (t == 0) ? 0 : s[t - 1];
}

__global__ __launch_bounds__(256) void k_emit(const int* __restrict__ cnt_dst,
                                              const int* __restrict__ offs,
                                              int* __restrict__ row_ptr,
                                              int* __restrict__ cursor) {
    __shared__ int s[256];
    int t = threadIdx.x;
    int i = blockIdx.x * 256 + t;
    int v = 0;
    if (i < NN)
        v = cnt_dst[i] + cnt_dst[NN + i] + cnt_dst[2 * NN + i] + cnt_dst[3 * NN + i];
    s[t] = v;
    __syncthreads();
    for (int off = 1; off < 256; off <<= 1) {
        int u = (t >= off) ? s[t - off] : 0;
        __syncthreads();
        s[t] += u;
        __syncthreads();
    }
    if (i < NN) {
        int ex = offs[blockIdx.x] + s[t] - v;
        row_ptr[i] = ex;
        cursor[i] = ex;
    }
    if (i == NN - 1) row_ptr[NN] = TE;
}

// fill CSR: packed 8B per edge: hi32 = weight bits, lo32 = src | r<<16
__global__ __launch_bounds__(256) void k_fill(const int* __restrict__ src,
                                              const int* __restrict__ dst,
                                              const float* __restrict__ nsrc,
                                              const float* __restrict__ ndst,
                                              int* __restrict__ cursor,
                                              unsigned long long* __restrict__ edges) {
    int i = blockIdx.x * 256 + threadIdx.x;
    if (i >= TE) return;
    int r = i / EE;
    int s = src[i], d = dst[i];
    int pos = atomicAdd(&cursor[d], 1);
    float w = nsrc[r * NN + s] * ndst[r * NN + d];
    unsigned long long pk = ((unsigned long long)__float_as_uint(w) << 32)
                          | (unsigned)(s | (r << 16));
    edges[pos] = pk;
}

// ---------------- converts ----------------
__global__ __launch_bounds__(256) void k_cvt_x(const float4* __restrict__ x4,
                                               uint2* __restrict__ o, int n4) {
    int i = blockIdx.x * 256 + threadIdx.x;
    if (i >= n4) return;
    float4 v = x4[i];
    o[i] = make_uint2(pack2(v.x, v.y), pack2(v.z, v.w));
}

// Bt[n][k] = bf16(basis[k][n]); basis flat [256][BN]
__global__ __launch_bounds__(256) void k_cvt_bt(const float* __restrict__ B,
                                                unsigned short* __restrict__ Bt, int BN) {
    int o = blockIdx.x * 256 + threadIdx.x;
    if (o >= BN * 256) return;
    int k = o & 255, n = o >> 8;
    Bt[o] = f2bf(B[k * BN + n]);
}

// ---------------- aggregation: one wave per dst node, bf16 gather ----------------
// hb: bf16 rows of 128 (= 64 uints). Mb: bf16 rows of 256 (= 128 uints).
__global__ __launch_bounds__(256) void k_agg(const unsigned* __restrict__ hb,
                                             const int* __restrict__ row_ptr,
                                             const unsigned long long* __restrict__ edges,
                                             const float* __restrict__ coeff,
                                             unsigned* __restrict__ Mb) {
    int wave = (blockIdx.x * 256 + threadIdx.x) >> 6;
    int lane = threadIdx.x & 63;
    if (wave >= NN) return;

    float c0[RR], c1[RR];
#pragma unroll
    for (int r = 0; r < RR; r++) {
        c0[r] = coeff[r * 2 + 0];
        c1[r] = coeff[r * 2 + 1];
    }

    int e0 = row_ptr[wave], e1 = row_ptr[wave + 1];
    float a00 = 0.f, a01 = 0.f, a10 = 0.f, a11 = 0.f;

    int e = e0;
    for (; e + 3 < e1; e += 4) {
        unsigned long long pk0 = edges[e + 0];
        unsigned long long pk1 = edges[e + 1];
        unsigned long long pk2 = edges[e + 2];
        unsigned long long pk3 = edges[e + 3];
        unsigned p0 = (unsigned)pk0, p1 = (unsigned)pk1;
        unsigned p2 = (unsigned)pk2, p3 = (unsigned)pk3;
        unsigned hv0 = hb[(p0 & 0xFFFF) * 64u + lane];
        unsigned hv1 = hb[(p1 & 0xFFFF) * 64u + lane];
        unsigned hv2 = hb[(p2 & 0xFFFF) * 64u + lane];
        unsigned hv3 = hb[(p3 & 0xFFFF) * 64u + lane];
#pragma unroll
        for (int j = 0; j < 4; j++) {
            unsigned p = (j == 0 ? p0 : j == 1 ? p1 : j == 2 ? p2 : p3);
            unsigned hv = (j == 0 ? hv0 : j == 1 ? hv1 : j == 2 ? hv2 : hv3);
            unsigned long long pk = (j == 0 ? pk0 : j == 1 ? pk1 : j == 2 ? pk2 : pk3);
            float w = __uint_as_float((unsigned)(pk >> 32));
            float h0 = __uint_as_float(hv << 16);
            float h1 = __uint_as_float(hv & 0xFFFF0000u);
            int r = (p >> 16) & 3;
            float wa = c0[r] * w, wb = c1[r] * w;
            a00 += wa * h0; a01 += wa * h1;
            a10 += wb * h0; a11 += wb * h1;
        }
    }
    for (; e < e1; e++) {
        unsigned long long pk = edges[e];
        unsigned p = (unsigned)pk;
        float w = __uint_as_float((unsigned)(pk >> 32));
        unsigned hv = hb[(p & 0xFFFF) * 64u + lane];
        float h0 = __uint_as_float(hv << 16);
        float h1 = __uint_as_float(hv & 0xFFFF0000u);
        int r = (p >> 16) & 3;
        float wa = c0[r] * w, wb = c1[r] * w;
        a00 += wa * h0; a01 += wa * h1;
        a10 += wb * h0; a11 += wb * h1;
    }

    Mb[(size_t)wave * 128 + lane] = pack2(a00, a01);
    Mb[(size_t)wave * 128 + 64 + lane] = pack2(a10, a11);
}

// ---------------- MFMA bf16 GEMM: C[N,BN] = Mb[N,256] @ B[256,BN] ----------------
// A row-major bf16; Bt = B^T row-major bf16 [BN][256] (k-contiguous).
// BF16OUT: relu + bf16 store (next layer input); else fp32 store (final out).
template <int BN, bool BF16OUT>
__global__ __launch_bounds__(256) void k_gemm(const unsigned short* __restrict__ A,
                                              const unsigned short* __restrict__ Bt,
                                              void* __restrict__ Cout) {
    int wave = threadIdx.x >> 6, lane = threadIdx.x & 63;
    int row0 = blockIdx.x * 64 + wave * 16;
    if (row0 >= NN) return;
    int m = lane & 15, q = lane >> 4;
    const int NT = BN / 16;

    frag_cd acc[NT];
#pragma unroll
    for (int ct = 0; ct < NT; ct++) acc[ct] = (frag_cd){0.f, 0.f, 0.f, 0.f};

    const size_t abase = (size_t)(row0 + m) * 256 + q * 8;
#pragma unroll
    for (int kc = 0; kc < 8; kc++) {
        frag_ab a = *(const frag_ab*)(A + abase + kc * 32);
#pragma unroll
        for (int ct = 0; ct < NT; ct++) {
            frag_ab b = *(const frag_ab*)(Bt + (size_t)(ct * 16 + m) * 256 + kc * 32 + q * 8);
            acc[ct] = __builtin_amdgcn_mfma_f32_16x16x32_bf16(a, b, acc[ct], 0, 0, 0);
        }
    }

#pragma unroll
    for (int ct = 0; ct < NT; ct++) {
#pragma unroll
        for (int i = 0; i < 4; i++) {
            int row = row0 + q * 4 + i;
            int col = ct * 16 + m;
            float v = acc[ct][i];
            if (BF16OUT) {
                v = fmaxf(v, 0.f);
                ((unsigned short*)Cout)[(size_t)row * BN + col] = f2bf(v);
            } else {
                ((float*)Cout)[(size_t)row * BN + col] = v;
            }
        }
    }
}

// ---------------- host ----------------

extern "C" void kernel_launch(void* const* d_in, const int* in_sizes, int n_in,
                              void* d_out, int out_size, void* d_ws, size_t ws_size,
                              hipStream_t stream) {
    const float* x      = (const float*)d_in[0];
    const int*   src    = (const int*)d_in[1];
    const int*   dst    = (const int*)d_in[2];
    const float* basis0 = (const float*)d_in[3];
    const float* coeff0 = (const float*)d_in[4];
    const float* basis1 = (const float*)d_in[5];
    const float* coeff1 = (const float*)d_in[6];
    const float* basis2 = (const float*)d_in[7];
    const float* coeff2 = (const float*)d_in[8];
    float* out = (float*)d_out;

    char* p = (char*)d_ws;
    auto alloc = [&](size_t bytes) {
        char* r = p;
        p += (bytes + 255) & ~(size_t)255;
        return r;
    };
    int*   cnt_src = (int*)alloc((size_t)RR * NN * 4);
    int*   cnt_dst = (int*)alloc((size_t)RR * NN * 4);
    float* nsrc    = (float*)alloc((size_t)RR * NN * 4);
    float* ndst    = (float*)alloc((size_t)RR * NN * 4);
    int*   row_ptr = (int*)alloc((size_t)(NN + 1) * 4);
    int*   cursor  = (int*)alloc((size_t)NN * 4);
    int*   part    = (int*)alloc((size_t)SCB * 4);
    int*   offs    = (int*)alloc((size_t)SCB * 4);
    unsigned long long* edges = (unsigned long long*)alloc((size_t)TE * 8);
    unsigned* Mb   = (unsigned*)alloc((size_t)NN * 128 * 4);        // bf16 [N][256]
    unsigned* Hb   = (unsigned*)alloc((size_t)NN * 64 * 4);         // bf16 [N][128]
    unsigned* Xb   = (unsigned*)alloc((size_t)NN * 64 * 4);         // bf16 [N][128]
    unsigned short* Bt0 = (unsigned short*)alloc((size_t)128 * 256 * 2);
    unsigned short* Bt1 = (unsigned short*)alloc((size_t)128 * 256 * 2);
    unsigned short* Bt2 = (unsigned short*)alloc((size_t)64 * 256 * 2);

    // setup
    k_cvt_x<<<(NN * 32 + 255) / 256, 256, 0, stream>>>((const float4*)x, (uint2*)Xb, NN * 32);
    k_cvt_bt<<<(128 * 256 + 255) / 256, 256, 0, stream>>>(basis0, Bt0, 128);
    k_cvt_bt<<<(128 * 256 + 255) / 256, 256, 0, stream>>>(basis1, Bt1, 128);
    k_cvt_bt<<<(64 * 256 + 255) / 256, 256, 0, stream>>>(basis2, Bt2, 64);
    k_hist<<<64, 1024, 0, stream>>>(src, dst, cnt_src, cnt_dst);
    k_norms<<<(RR * NN + 255) / 256, 256, 0, stream>>>(cnt_src, cnt_dst, nsrc, ndst);
    k_partial<<<SCB, 256, 0, stream>>>(cnt_dst, part);
    k_scan_small<<<1, 256, 0, stream>>>(part, offs);
    k_emit<<<SCB, 256, 0, stream>>>(cnt_dst, offs, row_ptr, cursor);
    k_fill<<<(TE + 255) / 256, 256, 0, stream>>>(src, dst, nsrc, ndst, cursor, edges);

    int aggBlocks = NN / 4;
    int gemmBlocks = (NN + 63) / 64;   // 782

    // layer 0: Xb -> Mb -> Hb (relu, bf16)
    k_agg<<<aggBlocks, 256, 0, stream>>>(Xb, row_ptr, edges, coeff0, Mb);
    k_gemm<128, true><<<gemmBlocks, 256, 0, stream>>>((const unsigned short*)Mb, Bt0, Hb);
    // layer 1
    k_agg<<<aggBlocks, 256, 0, stream>>>(Hb, row_ptr, edges, coeff1, Mb);
    k_gemm<128, true><<<gemmBlocks, 256, 0, stream>>>((const unsigned short*)Mb, Bt1, Hb);
    // layer 2: final, fp32 out, no relu
    k_agg<<<aggBlocks, 256, 0, stream>>>(Hb, row_ptr, edges, coeff2, Mb);
    k_gemm<64, false><<<gemmBlocks, 256, 0, stream>>>((const unsigned short*)Mb, Bt2, out);
}